// Round 3
// baseline (1444.982 us; speedup 1.0000x reference)
//
#include <hip/hip_runtime.h>
#include <cstdint>
#include <cstddef>

// ---------------------------------------------------------------------------
// AutoFormer forward, MI355X. ALL inputs/outputs are FP32 (per reference —
// the "(bf16, ...)" in the harness error label is a hardcoded format string).
// Internals: Q/K GEMMs in bf16 MFMA (fp32 accumulate), corr in fp32 VALU.
// B=8, L=2048, D=1024, H=16, E=64, TOPK=int(3*ln(2048))=22.
//
// Buffers:
//   ws:    WqT/WkT (bf16, 2 MiB ea), Qt (bf16 [B*D,L], 32 MiB), smalls (<1 MiB)
//   d_out: out0 region [16M fp32] doubles as Kt/corrWs bf16 staging (32 MiB);
//          bcast_out overwrites out0 LAST, after corr_transpose consumed it.
// ---------------------------------------------------------------------------

#define TOPK 22

typedef __attribute__((ext_vector_type(8))) short short8;
typedef __attribute__((ext_vector_type(4))) float f32x4;

__device__ __forceinline__ float bf2f(unsigned short u) {
  union { unsigned int i; float f; } w;
  w.i = ((unsigned int)u) << 16;
  return w.f;
}
__device__ __forceinline__ unsigned short f2bf(float f) {
  union { float f; unsigned int i; } w;
  w.f = f;
  unsigned int x = w.i;
  x += 0x7fffu + ((x >> 16) & 1u);  // RNE
  return (unsigned short)(x >> 16);
}

// ---------------------------------------------------------------------------
// 1. Weight transpose + fp32->bf16: WT[n][k] = bf16(W[k][n]), z=0:Wq z=1:Wk
// ---------------------------------------------------------------------------
__global__ __launch_bounds__(256) void transpose_w(
    const float* __restrict__ Wq, const float* __restrict__ Wk,
    unsigned short* __restrict__ WqT, unsigned short* __restrict__ WkT) {
  __shared__ unsigned short T[64][72];
  const float* src = blockIdx.z ? Wk : Wq;
  unsigned short* dst = blockIdx.z ? WkT : WqT;
  const int k0 = blockIdx.x * 64;
  const int n0 = blockIdx.y * 64;
  const int c = threadIdx.x & 63;
  const int r0 = threadIdx.x >> 6;
#pragma unroll
  for (int p = 0; p < 16; ++p) {
    const int r = r0 + 4 * p;  // k-local
    T[c][r] = f2bf(src[(size_t)(k0 + r) * 1024 + n0 + c]);  // coalesced read
  }
  __syncthreads();
#pragma unroll
  for (int p = 0; p < 16; ++p) {
    const int nn = r0 + 4 * p;  // n-local
    dst[(size_t)(n0 + nn) * 1024 + k0 + c] = T[nn][c];  // coalesced write
  }
}

// ---------------------------------------------------------------------------
// 2. MFMA bf16 GEMM: out = A(fp32)[16384,1024] @ W + bias(fp32), written
//    transposed bf16 as outT[b*1024+n][l]. Tile 128x128, BK=32, 4 waves,
//    16x16x32 MFMA. A converted fp32->bf16 during staging; WT already bf16.
// ---------------------------------------------------------------------------
__global__ __launch_bounds__(256, 2) void gemm_qk(
    const float* __restrict__ A,
    const unsigned short* __restrict__ WT,
    const float* __restrict__ bias,
    unsigned short* __restrict__ outT) {
  __shared__ __align__(16) unsigned short smem[16384];  // 32 KB
  unsigned short* As = smem;         // [128][32]
  unsigned short* Bs = smem + 4096;  // [128][32]

  const int tid = threadIdx.x;
  const int lane = tid & 63;
  const int w = tid >> 6;
  const int wr = w >> 1, wc = w & 1;
  const int m0 = blockIdx.x * 128;
  const int n0 = blockIdx.y * 128;
  const int l15 = lane & 15;
  const int quad = lane >> 4;

  f32x4 acc[4][4];
#pragma unroll
  for (int i = 0; i < 4; ++i)
#pragma unroll
    for (int j = 0; j < 4; ++j)
#pragma unroll
      for (int r = 0; r < 4; ++r) acc[i][j][r] = 0.f;

  for (int k0 = 0; k0 < 1024; k0 += 32) {
    __syncthreads();
#pragma unroll
    for (int h = 0; h < 2; ++h) {
      const int c = tid + h * 256;  // chunk 0..511
      const int row = c >> 2;       // 0..127
      const int kc = (c & 3) * 8;   // element offset in row
      // A: 8 fp32 -> 8 bf16
      const float* ap = A + (size_t)(m0 + row) * 1024 + k0 + kc;
      const float4 a0 = *reinterpret_cast<const float4*>(ap);
      const float4 a1 = *reinterpret_cast<const float4*>(ap + 4);
      uint4 pa;
      pa.x = f2bf(a0.x) | ((unsigned int)f2bf(a0.y) << 16);
      pa.y = f2bf(a0.z) | ((unsigned int)f2bf(a0.w) << 16);
      pa.z = f2bf(a1.x) | ((unsigned int)f2bf(a1.y) << 16);
      pa.w = f2bf(a1.z) | ((unsigned int)f2bf(a1.w) << 16);
      *reinterpret_cast<uint4*>(As + row * 32 + kc) = pa;
      // B: already bf16
      uint4 vb = *reinterpret_cast<const uint4*>(WT + (size_t)(n0 + row) * 1024 + k0 + kc);
      *reinterpret_cast<uint4*>(Bs + row * 32 + kc) = vb;
    }
    __syncthreads();

    short8 af[4], bfr[4];
#pragma unroll
    for (int mt = 0; mt < 4; ++mt)
      af[mt] = *reinterpret_cast<const short8*>(As + (wr * 64 + mt * 16 + l15) * 32 + quad * 8);
#pragma unroll
    for (int nt = 0; nt < 4; ++nt)
      bfr[nt] = *reinterpret_cast<const short8*>(Bs + (wc * 64 + nt * 16 + l15) * 32 + quad * 8);
#pragma unroll
    for (int mt = 0; mt < 4; ++mt)
#pragma unroll
      for (int nt = 0; nt < 4; ++nt)
        acc[mt][nt] = __builtin_amdgcn_mfma_f32_16x16x32_bf16(af[mt], bfr[nt], acc[mt][nt], 0, 0, 0);
  }

  __syncthreads();
  // epilogue: bias + pack transposed into LDS Cs[n_local][m_local] (bf16)
  unsigned short* Cs = smem;  // [128][128] bf16 = 32 KB
#pragma unroll
  for (int nt = 0; nt < 4; ++nt) {
    const int n_local = wc * 64 + nt * 16 + l15;
    const float bv = bias[n0 + n_local];
#pragma unroll
    for (int mt = 0; mt < 4; ++mt) {
      const int mbase = wr * 64 + mt * 16 + quad * 4;
#pragma unroll
      for (int r = 0; r < 4; ++r)
        Cs[n_local * 128 + mbase + r] = f2bf(acc[mt][nt][r] + bv);
    }
  }
  __syncthreads();

  const int b = m0 >> 11;    // m0 / 2048
  const int l0 = m0 & 2047;
  for (int it = tid; it < 2048; it += 256) {
    const int rowi = it >> 4;  // n_local
    const int ci = it & 15;    // 16B chunk
    uint4 v = *reinterpret_cast<const uint4*>(Cs + rowi * 128 + ci * 8);
    *reinterpret_cast<uint4*>(outT + (size_t)(b * 1024 + n0 + rowi) * 2048 + l0 + ci * 8) = v;
  }
}

// ---------------------------------------------------------------------------
// 3. V projection, rows l=0..7 only (the %8 quirk): vsmall[b*8+t][n] fp32
// ---------------------------------------------------------------------------
__global__ __launch_bounds__(256) void vsmall_kernel(
    const float* __restrict__ values,
    const float* __restrict__ Wv,
    const float* __restrict__ bv,
    float* __restrict__ out) {
  __shared__ float xr[1024];
  const int m = blockIdx.x;  // 0..63
  const int b = m >> 3, t = m & 7;
  const float* row = values + ((size_t)b * 2048 + t) * 1024;
  for (int i = threadIdx.x; i < 1024; i += 256) xr[i] = row[i];
  __syncthreads();
  const int n = blockIdx.y * 256 + threadIdx.x;
  float acc = 0.f;
#pragma unroll 8
  for (int k = 0; k < 1024; ++k) acc += xr[k] * Wv[(size_t)k * 1024 + n];
  out[(size_t)m * 1024 + n] = acc + bv[n];
}

// ---------------------------------------------------------------------------
// 4. Per-series circular correlation + top-22 + softmax + mod-8 aggregation.
//    One 256-thread block per series s = b*1024 + n.
//    Padded LDS addr(u) = u + (u>>3): thread-base stride 9 -> conflict-free.
//    corrOut aliases Kt (row fully read before row write; one block per row).
// ---------------------------------------------------------------------------
__global__ __launch_bounds__(256, 4) void corr_topk(
    const unsigned short* __restrict__ Qt,
    const unsigned short* Kt,
    const float* __restrict__ vsmall,
    unsigned short* corrOut,
    float* __restrict__ agg) {
  __shared__ __align__(16) float qs[2048];   // plain; read via uniform float4
  __shared__ float ksp[2324];                // padded k + 16-elem replica
  __shared__ float csp[2304];                // padded corr for top-k
  __shared__ float sel_val[TOPK];
  __shared__ int sel_idx[TOPK];
  __shared__ float wred[4];
  __shared__ int ired[4];
  __shared__ float wsum[8];

  const int tid = threadIdx.x;
  const int s = blockIdx.x;
  const size_t base = (size_t)s * 2048;

  {
    uint4 qv = reinterpret_cast<const uint4*>(Qt + base)[tid];
    uint4 kv = reinterpret_cast<const uint4*>(Kt + base)[tid];
    float qf[8], kf[8];
    qf[0] = bf2f((unsigned short)(qv.x & 0xffff)); qf[1] = bf2f((unsigned short)(qv.x >> 16));
    qf[2] = bf2f((unsigned short)(qv.y & 0xffff)); qf[3] = bf2f((unsigned short)(qv.y >> 16));
    qf[4] = bf2f((unsigned short)(qv.z & 0xffff)); qf[5] = bf2f((unsigned short)(qv.z >> 16));
    qf[6] = bf2f((unsigned short)(qv.w & 0xffff)); qf[7] = bf2f((unsigned short)(qv.w >> 16));
    kf[0] = bf2f((unsigned short)(kv.x & 0xffff)); kf[1] = bf2f((unsigned short)(kv.x >> 16));
    kf[2] = bf2f((unsigned short)(kv.y & 0xffff)); kf[3] = bf2f((unsigned short)(kv.y >> 16));
    kf[4] = bf2f((unsigned short)(kv.z & 0xffff)); kf[5] = bf2f((unsigned short)(kv.z >> 16));
    kf[6] = bf2f((unsigned short)(kv.w & 0xffff)); kf[7] = bf2f((unsigned short)(kv.w >> 16));
#pragma unroll
    for (int i = 0; i < 8; ++i) qs[tid * 8 + i] = qf[i];
#pragma unroll
    for (int i = 0; i < 8; ++i) ksp[tid * 9 + i] = kf[i];
    if (tid < 2) {  // replicate k[0..15] at logical 2048..2063
#pragma unroll
      for (int i = 0; i < 8; ++i) ksp[2304 + tid * 9 + i] = kf[i];
    }
  }
  __syncthreads();

  // corr[tau] = sum_t q[t]*k[(t-tau)&2047]; thread owns tau = t0..t0+7
  const int t0 = tid * 8;
  float accv[8];
#pragma unroll
  for (int i = 0; i < 8; ++i) accv[i] = 0.f;

  const float4* qs4 = reinterpret_cast<const float4*>(qs);

  for (int t = 0; t < 2048; t += 8) {
    const float4 q0 = qs4[t >> 2];       // wave-uniform broadcast
    const float4 q1 = qs4[(t >> 2) + 1];
    const float qv[8] = {q0.x, q0.y, q0.z, q0.w, q1.x, q1.y, q1.z, q1.w};
    // window: kw[x] = k[(t - t0 - 8 + x) & 2047], x in 1..15 used
    const int wst = (t - t0 - 8) & 2047;  // multiple of 8
    const int pb = (wst >> 3) * 9;        // padded base
    float kcf[16];
#pragma unroll
    for (int x = 1; x < 16; ++x) kcf[x] = ksp[pb + x + (x >> 3)];
#pragma unroll
    for (int i = 0; i < 8; ++i)
#pragma unroll
      for (int j = 0; j < 8; ++j)
        accv[i] += qv[j] * kcf[8 + j - i];
  }

#pragma unroll
  for (int i = 0; i < 8; ++i) csp[tid * 9 + i] = accv[i];
  {
    uint4 pk;
    pk.x = f2bf(accv[0]) | ((unsigned int)f2bf(accv[1]) << 16);
    pk.y = f2bf(accv[2]) | ((unsigned int)f2bf(accv[3]) << 16);
    pk.z = f2bf(accv[4]) | ((unsigned int)f2bf(accv[5]) << 16);
    pk.w = f2bf(accv[6]) | ((unsigned int)f2bf(accv[7]) << 16);
    reinterpret_cast<uint4*>(corrOut + base)[tid] = pk;  // overwrites Kt row s
  }
  __syncthreads();

  // top-22 (value desc, lower index on ties)
  for (int r = 0; r < TOPK; ++r) {
    float bv = -3.4e38f;
    int bi = 0;
#pragma unroll
    for (int i = 0; i < 8; ++i) {
      const float v = csp[tid * 9 + i];
      if (v > bv) { bv = v; bi = t0 + i; }
    }
#pragma unroll
    for (int off = 32; off > 0; off >>= 1) {
      const float ov = __shfl_down(bv, off);
      const int oi = __shfl_down(bi, off);
      if (ov > bv || (ov == bv && oi < bi)) { bv = ov; bi = oi; }
    }
    if ((tid & 63) == 0) { wred[tid >> 6] = bv; ired[tid >> 6] = bi; }
    __syncthreads();
    if (tid == 0) {
      float mv = wred[0];
      int mi = ired[0];
      for (int w2 = 1; w2 < 4; ++w2)
        if (wred[w2] > mv || (wred[w2] == mv && ired[w2] < mi)) { mv = wred[w2]; mi = ired[w2]; }
      sel_val[r] = mv;
      sel_idx[r] = mi;
      csp[mi + (mi >> 3)] = -3.4e38f;
    }
    __syncthreads();
  }

  if (tid == 0) {
    const float m = sel_val[0];
    float e[TOPK], ssum = 0.f;
    for (int r = 0; r < TOPK; ++r) { e[r] = __expf(sel_val[r] - m); ssum += e[r]; }
    const float inv = 1.f / ssum;
    float wacc[8];
    for (int c = 0; c < 8; ++c) wacc[c] = 0.f;
    for (int r = 0; r < TOPK; ++r) wacc[sel_idx[r] & 7] += e[r];
    for (int c = 0; c < 8; ++c) wsum[c] = wacc[c] * inv;
  }
  __syncthreads();

  if (tid < 8) {  // agg8[r] = sum_c wsum[c] * v[(r+c)&7]
    const int b = s >> 10, n = s & 1023;
    float a = 0.f;
#pragma unroll
    for (int c = 0; c < 8; ++c)
      a += wsum[c] * vsmall[(size_t)(b * 8 + ((tid + c) & 7)) * 1024 + n];
    agg[(size_t)(b * 8 + tid) * 1024 + n] = a;
  }
}

// ---------------------------------------------------------------------------
// 5. Output projection on the 64 distinct rows: outSmall = agg @ Wo + bo
// ---------------------------------------------------------------------------
__global__ __launch_bounds__(256) void osmall_kernel(
    const float* __restrict__ aggin,
    const float* __restrict__ Wo,
    const float* __restrict__ bo,
    float* __restrict__ out) {
  __shared__ float xr[1024];
  const int m = blockIdx.x;
  const float* row = aggin + (size_t)m * 1024;
  for (int i = threadIdx.x; i < 1024; i += 256) xr[i] = row[i];
  __syncthreads();
  const int n = blockIdx.y * 256 + threadIdx.x;
  float acc = 0.f;
#pragma unroll 8
  for (int k = 0; k < 1024; ++k) acc += xr[k] * Wo[(size_t)k * 1024 + n];
  out[(size_t)m * 1024 + n] = acc + bo[n];
}

// ---------------------------------------------------------------------------
// 6. corrWs[b*1024+n][l] (bf16) -> out1[b][l][n] (fp32 tiled transpose)
//    MUST run BEFORE bcast_out (corrWs lives in the out0 region).
// ---------------------------------------------------------------------------
__global__ __launch_bounds__(256) void corr_transpose(
    const unsigned short* __restrict__ corrWs,
    float* __restrict__ out1) {
  __shared__ unsigned short T[64][72];
  const int bb = blockIdx.z;
  const int l0 = blockIdx.x * 64;
  const int n0 = blockIdx.y * 64;
  const int c = threadIdx.x & 63;
  const int r0 = threadIdx.x >> 6;
#pragma unroll
  for (int p = 0; p < 16; ++p) {
    const int r = r0 + 4 * p;  // n-local
    T[c][r] = corrWs[(size_t)(bb * 1024 + n0 + r) * 2048 + l0 + c];
  }
  __syncthreads();
#pragma unroll
  for (int p = 0; p < 16; ++p) {
    const int ll = r0 + 4 * p;  // l-local
    out1[(size_t)(bb * 2048 + l0 + ll) * 1024 + n0 + c] = bf2f(T[ll][c]);
  }
}

// ---------------------------------------------------------------------------
// 7. Broadcast out0[b,l,:] = outSmall[b*8 + (l&7), :] (fp32). Runs LAST.
// ---------------------------------------------------------------------------
__global__ __launch_bounds__(256) void bcast_out(
    const float* __restrict__ outSmall,
    float* __restrict__ out0) {
  const size_t i4 = (size_t)blockIdx.x * 256 + threadIdx.x;
  const size_t basee = i4 * 4;
  const int n = (int)(basee & 1023);
  const int l = (int)((basee >> 10) & 2047);
  const int b = (int)(basee >> 21);
  const float4 v = *reinterpret_cast<const float4*>(outSmall + ((size_t)(b * 8 + (l & 7)) << 10) + n);
  *reinterpret_cast<float4*>(out0 + basee) = v;
}

// ---------------------------------------------------------------------------
extern "C" void kernel_launch(void* const* d_in, const int* in_sizes, int n_in,
                              void* d_out, int out_size, void* d_ws, size_t ws_size,
                              hipStream_t stream) {
  const float* queries = (const float*)d_in[0];
  const float* keys    = (const float*)d_in[1];
  const float* values  = (const float*)d_in[2];
  const float* Wq = (const float*)d_in[3];
  const float* bq = (const float*)d_in[4];
  const float* Wk = (const float*)d_in[5];
  const float* bk = (const float*)d_in[6];
  const float* Wv = (const float*)d_in[7];
  const float* bv = (const float*)d_in[8];
  const float* Wo = (const float*)d_in[9];
  const float* bo = (const float*)d_in[10];

  char* ws = (char*)d_ws;
  unsigned short* WqT = (unsigned short*)(ws);                    // 2 MiB bf16
  unsigned short* WkT = (unsigned short*)(ws + (2u << 20));       // 2 MiB bf16
  unsigned short* Qt  = (unsigned short*)(ws + (4u << 20));       // 32 MiB bf16 [B*D, L]
  float* vsmall   = (float*)(ws + (36u << 20));                   // 256 KiB
  float* aggbuf   = (float*)(ws + (36u << 20) + (256u << 10));    // 256 KiB
  float* outSmall = (float*)(ws + (36u << 20) + (512u << 10));    // 256 KiB
  // total ws: 36.75 MiB

  float* out0 = (float*)d_out;                   // [8,2048,1024] fp32
  float* out1 = out0 + (size_t)16777216;         // [8,2048,1024] fp32
  // Kt bf16 staging (32 MiB) lives in the out0 region (64 MiB fp32);
  // corr output aliases it row-by-row; bcast_out overwrites out0 last.
  unsigned short* Kt = (unsigned short*)d_out;
  unsigned short* corrWs = Kt;

  transpose_w<<<dim3(16, 16, 2), 256, 0, stream>>>(Wq, Wk, WqT, WkT);
  gemm_qk<<<dim3(128, 8), 256, 0, stream>>>(queries, WqT, bq, Qt);
  gemm_qk<<<dim3(128, 8), 256, 0, stream>>>(keys, WkT, bk, Kt);
  vsmall_kernel<<<dim3(64, 4), 256, 0, stream>>>(values, Wv, bv, vsmall);
  corr_topk<<<8192, 256, 0, stream>>>(Qt, Kt, vsmall, corrWs, aggbuf);
  osmall_kernel<<<dim3(64, 4), 256, 0, stream>>>(aggbuf, Wo, bo, outSmall);
  corr_transpose<<<dim3(32, 16, 8), 256, 0, stream>>>(corrWs, out1);
  bcast_out<<<16384, 256, 0, stream>>>(outSmall, out0);
}